// Round 3
// baseline (667.286 us; speedup 1.0000x reference)
//
#include <hip/hip_runtime.h>
#include <hip/hip_bf16.h>

// out[M,N] = data[M,K] @ (mask*weight)[N,K]^T + bias[N];  M=8192, N=K=4096, fp32.
// R3: GEMM restructure. BK=64 (32 MFMA per barrier pair, halves barrier-drain
// count vs BK=32) + XOR-swizzled LDS layout (conflict-free ds_read_b128; the
// swizzle is applied to the GLOBAL source column per lane because
// global_load_lds forces LDS dest = base + lane*16 and forbids padding)
// + grid swizzle (8 bm-rows per bn sweep) for A-tile L2 locality.
// cvt kernel unchanged (at BW floor); residual ~270 us is harness-fixed.

#define Mdim 8192
#define Ndim 4096
#define Kdim 4096

typedef __bf16 bf16x8 __attribute__((ext_vector_type(8)));
typedef float f32x4 __attribute__((ext_vector_type(4)));

// round-to-nearest-even fp32 -> bf16 bits
__device__ inline unsigned short f2bf(float f) {
    union { float f; unsigned u; } v;
    v.f = f;
    unsigned r = v.u + 0x7fffu + ((v.u >> 16) & 1u);
    return (unsigned short)(r >> 16);
}

__device__ inline unsigned pack2(float a, float b) {
    return (unsigned)f2bf(a) | ((unsigned)f2bf(b) << 16);
}

#define GLOAD_LDS16(gp, lp)                                                     \
    __builtin_amdgcn_global_load_lds((const __attribute__((address_space(1))) void*)(gp), \
                                     (__attribute__((address_space(3))) void*)(lp), 16, 0, 0)

// ---- fused conversion: data->bf16 and (weight*mask)->bf16, 16B I/O ----
__global__ __launch_bounds__(256) void k_cvt_all(const float4* __restrict__ data,
                                                 const float4* __restrict__ weight,
                                                 const float4* __restrict__ mask,
                                                 uint4* __restrict__ Abf,
                                                 uint4* __restrict__ Bbf) {
    const int NA = Mdim * (Kdim / 8);
    const int NB = Ndim * (Kdim / 8);
    const int stride = gridDim.x * blockDim.x;
    for (int i = blockIdx.x * blockDim.x + threadIdx.x; i < NA + NB; i += stride) {
        if (i < NA) {
            const size_t j2 = 2 * (size_t)i;
            float4 v0 = data[j2], v1 = data[j2 + 1];
            uint4 o;
            o.x = pack2(v0.x, v0.y); o.y = pack2(v0.z, v0.w);
            o.z = pack2(v1.x, v1.y); o.w = pack2(v1.z, v1.w);
            Abf[i] = o;
        } else {
            const size_t j = (size_t)(i - NA);
            const size_t j2 = 2 * j;
            float4 w0 = weight[j2], w1 = weight[j2 + 1];
            float4 m0 = mask[j2],   m1 = mask[j2 + 1];
            uint4 o;
            o.x = pack2(w0.x * m0.x, w0.y * m0.y);
            o.y = pack2(w0.z * m0.z, w0.w * m0.w);
            o.z = pack2(w1.x * m1.x, w1.y * m1.y);
            o.w = pack2(w1.z * m1.z, w1.w * m1.w);
            Bbf[j] = o;
        }
    }
}

// ---- bf16 MFMA GEMM: C = A * B^T + bias ----
// Block 256 = 4 waves, tile 128x128, BK=64. LDS row-major [128][64] with
// per-8-row XOR chunk swizzle: LDS[row][chunk] holds global chunk (chunk ^ (row&7)).
__global__ __launch_bounds__(256) void k_gemm(const unsigned short* __restrict__ A,
                                              const unsigned short* __restrict__ B,
                                              const float* __restrict__ bias,
                                              float* __restrict__ out) {
    __shared__ unsigned short As[128 * 64];  // 16 KB
    __shared__ unsigned short Bs[128 * 64];  // 16 KB

    const int tid  = threadIdx.x;
    const int lane = tid & 63;
    const int wave = tid >> 6;
    const int wm   = (wave >> 1) * 64;
    const int wn   = (wave & 1) * 64;

    // grid swizzle: consecutive bids sweep 8 bm-rows before advancing bn
    const int bid = blockIdx.y * gridDim.x + blockIdx.x;  // x is dispatch-fastest
    const int per_group = 8 * 32;                          // 8 bm-rows x 32 bn
    const int gidx = bid / per_group;
    const int rem  = bid % per_group;
    const int bm = (gidx * 8 + (rem & 7)) * 128;
    const int bn = (rem >> 3) * 128;

    // staging: per wave 4 chunks of 8 rows x 64 cols for A and B.
    // lane l: row-in-chunk sr = l>>3 (also the xor key), col chunk (l&7)^sr.
    const int sr = lane >> 3;
    const int sc = ((lane & 7) ^ sr) * 8;
    const unsigned short* Ag = A + (size_t)(bm + wave * 32 + sr) * Kdim + sc;
    const unsigned short* Bg = B + (size_t)(bn + wave * 32 + sr) * Kdim + sc;
    unsigned short* Al = As + (wave * 32) * 64 + lane * 8;  // +c*512 per chunk
    unsigned short* Bl = Bs + (wave * 32) * 64 + lane * 8;

    f32x4 zero = {0.f, 0.f, 0.f, 0.f};
    f32x4 acc[4][4];
#pragma unroll
    for (int i = 0; i < 4; ++i)
#pragma unroll
        for (int j = 0; j < 4; ++j) acc[i][j] = zero;

    const int fr = lane & 15;   // fragment row
    const int fx = fr & 7;      // xor key for de-swizzle
    const int g0 = lane >> 4;   // k-chunk within a 32-wide K-half

    for (int k0 = 0; k0 < Kdim; k0 += 64) {
#pragma unroll
        for (int c = 0; c < 4; ++c) {
            GLOAD_LDS16(Ag + k0 + (size_t)(c * 8) * Kdim, Al + c * 512);
            GLOAD_LDS16(Bg + k0 + (size_t)(c * 8) * Kdim, Bl + c * 512);
        }
        __syncthreads();

#pragma unroll
        for (int kh = 0; kh < 2; ++kh) {
            const int ch = ((g0 + kh * 4) ^ fx) * 8;  // de-swizzled chunk offset
            bf16x8 af[4], bfr[4];
#pragma unroll
            for (int i = 0; i < 4; ++i)
                af[i] = *(const bf16x8*)&As[(wm + i * 16 + fr) * 64 + ch];
#pragma unroll
            for (int j = 0; j < 4; ++j)
                bfr[j] = *(const bf16x8*)&Bs[(wn + j * 16 + fr) * 64 + ch];
#pragma unroll
            for (int i = 0; i < 4; ++i)
#pragma unroll
                for (int j = 0; j < 4; ++j)
                    acc[i][j] = __builtin_amdgcn_mfma_f32_16x16x32_bf16(af[i], bfr[j], acc[i][j], 0, 0, 0);
        }
        __syncthreads();
    }

    // epilogue: C/D layout col=lane&15, row=(lane>>4)*4+reg  [measured m89/m91]
    const int col_base = bn + wn + (lane & 15);
    const int row_base = bm + wm + (lane >> 4) * 4;
#pragma unroll
    for (int j = 0; j < 4; ++j) {
        const int col = col_base + j * 16;
        const float bv = bias[col];
#pragma unroll
        for (int i = 0; i < 4; ++i) {
            const int row = row_base + i * 16;
            float* op = out + (size_t)row * Ndim + col;
#pragma unroll
            for (int r = 0; r < 4; ++r) op[(size_t)r * Ndim] = acc[i][j][r] + bv;
        }
    }
}

// ---- fallback (only if ws too small): naive fp32, correct but slow ----
__global__ void k_naive(const float* __restrict__ A, const float* __restrict__ W,
                        const float* __restrict__ Msk, const float* __restrict__ bias,
                        float* __restrict__ out) {
    int n = blockIdx.x * blockDim.x + threadIdx.x;
    int m = blockIdx.y;
    if (n >= Ndim) return;
    const float* a = A + (size_t)m * Kdim;
    const float* w = W + (size_t)n * Kdim;
    const float* mk = Msk + (size_t)n * Kdim;
    float s = 0.f;
    for (int k = 0; k < Kdim; ++k) s += a[k] * w[k] * mk[k];
    out[(size_t)m * Ndim + n] = s + bias[n];
}

extern "C" void kernel_launch(void* const* d_in, const int* in_sizes, int n_in,
                              void* d_out, int out_size, void* d_ws, size_t ws_size,
                              hipStream_t stream) {
    const float* data   = (const float*)d_in[0];
    const float* weight = (const float*)d_in[1];
    const float* mask   = (const float*)d_in[2];
    const float* bias   = (const float*)d_in[3];
    float* out = (float*)d_out;

    const size_t needA = (size_t)Mdim * Kdim * 2;  // 64 MiB
    const size_t needB = (size_t)Ndim * Kdim * 2;  // 32 MiB
    if (ws_size < needA + needB) {
        dim3 g((Ndim + 255) / 256, Mdim);
        k_naive<<<g, 256, 0, stream>>>(data, weight, mask, bias, out);
        return;
    }

    unsigned short* Abf = (unsigned short*)d_ws;
    unsigned short* Bbf = Abf + (size_t)Mdim * Kdim;

    k_cvt_all<<<4096, 256, 0, stream>>>((const float4*)data, (const float4*)weight,
                                        (const float4*)mask, (uint4*)Abf, (uint4*)Bbf);

    dim3 grid(Ndim / 128, Mdim / 128);  // (32, 64) = 2048 blocks
    k_gemm<<<grid, 256, 0, stream>>>(Abf, Bbf, bias, out);
}